// Round 3
// baseline (66.417 us; speedup 1.0000x reference)
//
#include <hip/hip_runtime.h>

#define NPART 128
#define NBATCH 256
#define NOUT 64
#define NIN 64

typedef __attribute__((ext_vector_type(8))) short short8;   // MFMA A/B frag (8 bf16)
typedef __attribute__((ext_vector_type(4))) float floatx4;  // MFMA C/D frag

__device__ __forceinline__ short f_to_bf16(float f) {
    union { unsigned int i; float f; } v; v.f = f;
    unsigned int b = v.i;
    unsigned int r = b + 0x7FFFu + ((b >> 16) & 1u);   // RNE; finite positives only here
    return (short)(r >> 16);
}

// out[b,p,o] = log( sum_i exp(x[b,p,i]) * exp(w[p,o,i]) ) - log( sum_i exp(w[p,o,i]) )
//            = logsumexp_i( x[b,p,i] + log_softmax(w[p,o,:])[i] )
//
// Zero-LDS design: MFMA 16x16x32 A/B fragments are 8 k-contiguous elements per
// lane, so each lane loads its 32 B slice of x / w directly from global,
// applies exp + bf16-cvt in-register, and issues MFMA. No staging, no barrier.
// wlse[o] = log(sum_i exp(w[o,i])) via shfl_xor(16/32) across the 4 q-lanes.
__global__ __launch_bounds__(256, 4) void sumlayer_kernel(
    const float* __restrict__ x,   // [NBATCH][NPART][NIN] fp32
    const float* __restrict__ w,   // [NPART][NOUT][NIN] fp32
    float* __restrict__ out)       // [NBATCH][NPART][NOUT] fp32
{
    const int p  = blockIdx.x;        // partition
    const int b0 = blockIdx.y * 32;   // batch tile origin (32 rows/block)
    const int t  = threadIdx.x;
    const int wv = t >> 6;            // wave 0..3
    const int l  = t & 63;
    const int ln = l & 15;            // m (batch row) for A, n (out node) for B
    const int q  = l >> 4;            // quad: k = q*8 + j
    const int r0 = (wv & 1) * 16;     // wave's batch-row block within the tile
    const int oh = (wv >> 1) * 32;    // wave's out-node half

    // ---- A fragments: exp(x[b0+r0+ln, p, k]), k in [q*8, q*8+8) and [32+q*8, ...)
    const float* xrow = x + (((size_t)(b0 + r0 + ln) * NPART + p) * NIN);
    float4 xa0 = *(const float4*)(xrow + q * 8);
    float4 xa1 = *(const float4*)(xrow + q * 8 + 4);
    float4 xa2 = *(const float4*)(xrow + 32 + q * 8);
    float4 xa3 = *(const float4*)(xrow + 32 + q * 8 + 4);
    short8 af0, af1;
    {
        const float v0[8] = {xa0.x, xa0.y, xa0.z, xa0.w, xa1.x, xa1.y, xa1.z, xa1.w};
        const float v1[8] = {xa2.x, xa2.y, xa2.z, xa2.w, xa3.x, xa3.y, xa3.z, xa3.w};
        #pragma unroll
        for (int j = 0; j < 8; ++j) af0[j] = f_to_bf16(__expf(v0[j]));
        #pragma unroll
        for (int j = 0; j < 8; ++j) af1[j] = f_to_bf16(__expf(v1[j]));
    }

    floatx4 acc[2];
    float wl[2];
    #pragma unroll
    for (int ot = 0; ot < 2; ++ot) {
        // B fragment: lane holds B[k = q*8+j][n = ln] = exp(w[p, o, k]), o = oh+ot*16+ln
        const int o = oh + ot * 16 + ln;
        const float* wrow = w + (((size_t)p * NOUT + o) * NIN);
        float4 wb0 = *(const float4*)(wrow + q * 8);
        float4 wb1 = *(const float4*)(wrow + q * 8 + 4);
        float4 wb2 = *(const float4*)(wrow + 32 + q * 8);
        float4 wb3 = *(const float4*)(wrow + 32 + q * 8 + 4);
        const float v0[8] = {wb0.x, wb0.y, wb0.z, wb0.w, wb1.x, wb1.y, wb1.z, wb1.w};
        const float v1[8] = {wb2.x, wb2.y, wb2.z, wb2.w, wb3.x, wb3.y, wb3.z, wb3.w};
        short8 bf0, bf1;
        float s = 0.f;
        #pragma unroll
        for (int j = 0; j < 8; ++j) { float e = __expf(v0[j]); s += e; bf0[j] = f_to_bf16(e); }
        #pragma unroll
        for (int j = 0; j < 8; ++j) { float e = __expf(v1[j]); s += e; bf1[j] = f_to_bf16(e); }
        // full-row sumexp for this lane's o: reduce across the 4 q-lanes
        s += __shfl_xor(s, 16);
        s += __shfl_xor(s, 32);
        wl[ot] = __logf(s);

        floatx4 c = {0.f, 0.f, 0.f, 0.f};
        c = __builtin_amdgcn_mfma_f32_16x16x32_bf16(af0, bf0, c, 0, 0, 0);
        c = __builtin_amdgcn_mfma_f32_16x16x32_bf16(af1, bf1, c, 0, 0, 0);
        acc[ot] = c;
    }

    // ---- epilogue: D layout col(n)=ln -> o, row(m)=q*4+r -> batch row
    #pragma unroll
    for (int ot = 0; ot < 2; ++ot) {
        const int o = oh + ot * 16 + ln;
        #pragma unroll
        for (int r = 0; r < 4; ++r) {
            const int b = b0 + r0 + q * 4 + r;
            out[((size_t)b * NPART + p) * NOUT + o] = __logf(acc[ot][r]) - wl[ot];
        }
    }
}

extern "C" void kernel_launch(void* const* d_in, const int* in_sizes, int n_in,
                              void* d_out, int out_size, void* d_ws, size_t ws_size,
                              hipStream_t stream) {
    const float* x = (const float*)d_in[0];   // fp32 [256,128,64]
    const float* w = (const float*)d_in[1];   // fp32 [128,64,64]
    float* out = (float*)d_out;               // fp32 [256,128,64]
    dim3 grid(NPART, NBATCH / 32);
    sumlayer_kernel<<<grid, dim3(256), 0, stream>>>(x, w, out);
}

// Round 4
// 63.267 us; speedup vs baseline: 1.0498x; 1.0498x over previous
//
#include <hip/hip_runtime.h>

#define NPART 128
#define NBATCH 256
#define NOUT 64
#define NIN 64
#define BROWS 32  // batch rows per block
#define LDK 72    // padded LDS row stride in bf16 elements (144 B -> max 2-way bank aliasing = free)

typedef __attribute__((ext_vector_type(8))) short short8;        // MFMA A/B frag (8 bf16)
typedef __attribute__((ext_vector_type(4))) float floatx4;       // MFMA C/D frag
typedef __attribute__((ext_vector_type(8))) unsigned short ushort8;

__device__ __forceinline__ unsigned short f_to_bf16(float f) {
    union { unsigned int i; float f; } v; v.f = f;
    unsigned int b = v.i;
    unsigned int r = b + 0x7FFFu + ((b >> 16) & 1u);   // RNE; finite positives only here
    return (unsigned short)(r >> 16);
}

// out[b,p,o] = log( sum_i exp(x[b,p,i]) * exp(w[p,o,i]) ) - log( sum_i exp(w[p,o,i]) )
//            = logsumexp_i( x[b,p,i] + log_softmax(w[p,o,:])[i] )
//
// R2 structure (coalesced global -> exp -> bf16 LDS -> MFMA), 32-row batch
// tiles for 1024 blocks = 4 blocks/CU latency overlap.
__global__ __launch_bounds__(256, 4) void sumlayer_kernel(
    const float* __restrict__ x,   // [NBATCH][NPART][NIN] fp32
    const float* __restrict__ w,   // [NPART][NOUT][NIN] fp32
    float* __restrict__ out)       // [NBATCH][NPART][NOUT] fp32
{
    __shared__ alignas(16) unsigned short Wlds[64 * LDK];     // bf16(exp(w[p]))
    __shared__ alignas(16) unsigned short Alds[BROWS * LDK];  // bf16(exp(x)) tile
    __shared__ float wlse[64];

    const int p  = blockIdx.x;            // partition
    const int b0 = blockIdx.y * BROWS;    // batch tile origin
    const int t  = threadIdx.x;

    // ---- stage bf16(exp(weight[p])) -> Wlds, wlse[o] = log(sum_i exp(w[o,:])) ----
    {
        const int row = t >> 2;           // 0..63 out-node
        const int sub = t & 3;            // 16 elems each
        const float* wrow = w + (((size_t)p * NOUT + row) * NIN + sub * 16);
        float vals[16];
        #pragma unroll
        for (int j = 0; j < 16; j += 4) {
            float4 v = *(const float4*)(wrow + j);
            vals[j] = v.x; vals[j+1] = v.y; vals[j+2] = v.z; vals[j+3] = v.w;
        }
        float s = 0.f;
        ushort8 e0, e1;
        #pragma unroll
        for (int j = 0; j < 8; ++j) { float e = __expf(vals[j]);     s += e; e0[j] = f_to_bf16(e); }
        #pragma unroll
        for (int j = 0; j < 8; ++j) { float e = __expf(vals[8 + j]); s += e; e1[j] = f_to_bf16(e); }
        unsigned short* dst = Wlds + row * LDK + sub * 16;
        *(ushort8*)(dst)     = e0;
        *(ushort8*)(dst + 8) = e1;
        // 4 sub-lanes of a row are adjacent lanes in one wave (4 | 64)
        s += __shfl_xor(s, 1);
        s += __shfl_xor(s, 2);
        if (sub == 0) wlse[row] = __logf(s);
    }

    // ---- stage bf16(exp(x[b0+row, p, :])) -> Alds (8 elems/thread, coalesced) ----
    {
        const int row = t >> 3;           // 0..31 batch row in tile
        const int sub = t & 7;            // 8 elems each
        const float* xrow = x + ((((size_t)(b0 + row)) * NPART + p) * NIN + sub * 8);
        float4 v0 = *(const float4*)(xrow);
        float4 v1 = *(const float4*)(xrow + 4);
        const float vals[8] = {v0.x, v0.y, v0.z, v0.w, v1.x, v1.y, v1.z, v1.w};
        ushort8 a0;
        #pragma unroll
        for (int j = 0; j < 8; ++j) a0[j] = f_to_bf16(__expf(vals[j]));
        *(ushort8*)(Alds + row * LDK + sub * 8) = a0;
    }

    __syncthreads();

    // ---- MFMA: wave -> 16 batch rows x 32 out-nodes ----
    const int wv = t >> 6;            // wave 0..3
    const int l  = t & 63;
    const int ln = l & 15;
    const int q  = l >> 4;            // quad: k = q*8 + j
    const int r0 = (wv & 1) * 16;     // batch-row block within tile
    const int oh = (wv >> 1) * 32;    // out-node half

    // A frag: lane holds A[m = r0+ln][k = q*8+j]
    const short8 a0 = *(const short8*)(Alds + (r0 + ln) * LDK + q * 8);
    const short8 a1 = *(const short8*)(Alds + (r0 + ln) * LDK + 32 + q * 8);

    floatx4 acc[2];
    #pragma unroll
    for (int ot = 0; ot < 2; ++ot) {
        const int o = oh + ot * 16 + ln;
        // B frag: lane holds B[k = q*8+j][n] = expw[o][k]
        const short8 bb0 = *(const short8*)(Wlds + o * LDK + q * 8);
        const short8 bb1 = *(const short8*)(Wlds + o * LDK + 32 + q * 8);
        floatx4 c = {0.f, 0.f, 0.f, 0.f};
        c = __builtin_amdgcn_mfma_f32_16x16x32_bf16(a0, bb0, c, 0, 0, 0);
        c = __builtin_amdgcn_mfma_f32_16x16x32_bf16(a1, bb1, c, 0, 0, 0);
        acc[ot] = c;
    }

    // ---- epilogue: D layout col(n)=ln -> o, row(m)=q*4+r -> batch row ----
    #pragma unroll
    for (int ot = 0; ot < 2; ++ot) {
        const int o = oh + ot * 16 + ln;
        const float wl = wlse[o];
        #pragma unroll
        for (int r = 0; r < 4; ++r) {
            const int b = b0 + r0 + q * 4 + r;
            out[((size_t)b * NPART + p) * NOUT + o] = __logf(acc[ot][r]) - wl;
        }
    }
}

extern "C" void kernel_launch(void* const* d_in, const int* in_sizes, int n_in,
                              void* d_out, int out_size, void* d_ws, size_t ws_size,
                              hipStream_t stream) {
    const float* x = (const float*)d_in[0];   // fp32 [256,128,64]
    const float* w = (const float*)d_in[1];   // fp32 [128,64,64]
    float* out = (float*)d_out;               // fp32 [256,128,64]
    dim3 grid(NPART, NBATCH / BROWS);
    sumlayer_kernel<<<grid, dim3(256), 0, stream>>>(x, w, out);
}